// Round 8
// baseline (750.815 us; speedup 1.0000x reference)
//
#include <hip/hip_runtime.h>
#include <hip/hip_bf16.h>
#include <math.h>

#define B_ 2
#define T_ 2048
#define C_ 768
#define H_ 12
#define D_ 64
#define HID_ 3072
#define NROW 4096   // B*T
#define N3C 2304    // 3*C

typedef short bf16x8 __attribute__((ext_vector_type(8)));
typedef float f32x4 __attribute__((ext_vector_type(4)));
typedef unsigned short u16;
typedef unsigned int u32;

__device__ inline u16 f2bf(float f) {
    u32 u = __float_as_uint(f);
    u32 r = (u + 0x7fffu + ((u >> 16) & 1u)) >> 16;  // RNE
    return (u16)r;
}

__device__ __forceinline__ void dma16(const float* g, float* lds) {
    // each lane: 16B from its g -> ldsbase + lane*16 (linear, wave-uniform base)
    __builtin_amdgcn_global_load_lds(
        (const __attribute__((address_space(1))) void*)g,
        (__attribute__((address_space(3))) void*)lds, 16, 0, 0);
}

// ---------------- weight / activation f32 -> bf16 convert ----------------
__global__ __launch_bounds__(256) void cvt_bf16_kernel(const float* __restrict__ s,
                                                       u16* __restrict__ d, int n) {
    int i = (blockIdx.x * 256 + threadIdx.x) * 4;
    if (i >= n) return;
    float4 v = *(const float4*)(s + i);
    ushort4 o;
    o.x = f2bf(v.x); o.y = f2bf(v.y); o.z = f2bf(v.z); o.w = f2bf(v.w);
    *(ushort4*)(d + i) = o;
}

// ---------------- LayerNorm (f32 in, bf16 out), one block per row ----------------
__global__ __launch_bounds__(256) void ln_kernel(const float* __restrict__ x,
                                                 const float* __restrict__ g,
                                                 const float* __restrict__ b,
                                                 u16* __restrict__ out) {
    int row = blockIdx.x, t = threadIdx.x;
    const float* xr = x + (size_t)row * C_;
    float v[3], s = 0.f, sq = 0.f;
#pragma unroll
    for (int i = 0; i < 3; i++) {
        v[i] = xr[i * 256 + t];
        s += v[i]; sq += v[i] * v[i];
    }
    for (int m = 32; m; m >>= 1) { s += __shfl_xor(s, m); sq += __shfl_xor(sq, m); }
    __shared__ float ss[4], ssq[4];
    int wid = t >> 6;
    if ((t & 63) == 0) { ss[wid] = s; ssq[wid] = sq; }
    __syncthreads();
    s = ss[0] + ss[1] + ss[2] + ss[3];
    sq = ssq[0] + ssq[1] + ssq[2] + ssq[3];
    float mu = s * (1.f / C_);
    float var = sq * (1.f / C_) - mu * mu;
    float rstd = rsqrtf(var + 1e-5f);
#pragma unroll
    for (int i = 0; i < 3; i++) {
        int c = i * 256 + t;
        out[(size_t)row * C_ + c] = f2bf((v[i] - mu) * rstd * g[c] + b[c]);
    }
}

// ---------------- bf16 MFMA GEMM: out = A[M,K] @ W[N,K]^T (+bias, epilogues) ----------------
template <int EPI>
__global__ __launch_bounds__(256) void gemm_kernel(const u16* __restrict__ A,
                                                   const u16* __restrict__ W,
                                                   const float* __restrict__ bias,
                                                   float* __restrict__ outf,
                                                   u16* __restrict__ outb,
                                                   const float* __restrict__ res,
                                                   const float* __restrict__ ls,
                                                   int N, int K) {
    __shared__ u16 Alds[128 * 64];
    __shared__ u16 Blds[128 * 64];
    int tid = threadIdx.x;
    int m0 = blockIdx.y * 128, n0 = blockIdx.x * 128;
    int lane = tid & 63, wid = tid >> 6;
    int wr = wid >> 1, wc = wid & 1;
    int lr = lane & 15, lq = lane >> 4;

    f32x4 acc[4][4];
#pragma unroll
    for (int i = 0; i < 4; i++)
#pragma unroll
        for (int j = 0; j < 4; j++) acc[i][j] = (f32x4){0.f, 0.f, 0.f, 0.f};

    int nk = K >> 6;
    const u16* Ab = A + (size_t)m0 * K;
    const u16* Wb = W + (size_t)n0 * K;
    bf16x8 ra[4], rb[4];
#pragma unroll
    for (int i = 0; i < 4; i++) {
        int c = tid + i * 256, row = c >> 3, j = c & 7;
        ra[i] = *(const bf16x8*)(Ab + (size_t)row * K + j * 8);
        rb[i] = *(const bf16x8*)(Wb + (size_t)row * K + j * 8);
    }
    for (int kt = 0; kt < nk; ++kt) {
        __syncthreads();
#pragma unroll
        for (int i = 0; i < 4; i++) {
            int c = tid + i * 256, row = c >> 3, j = c & 7;
            int off = row * 64 + ((j ^ (row & 7)) << 3);   // XOR-swizzled 16B blocks
            *(bf16x8*)(Alds + off) = ra[i];
            *(bf16x8*)(Blds + off) = rb[i];
        }
        __syncthreads();
        if (kt + 1 < nk) {
            int k0 = (kt + 1) << 6;
#pragma unroll
            for (int i = 0; i < 4; i++) {
                int c = tid + i * 256, row = c >> 3, j = c & 7;
                ra[i] = *(const bf16x8*)(Ab + (size_t)row * K + k0 + j * 8);
                rb[i] = *(const bf16x8*)(Wb + (size_t)row * K + k0 + j * 8);
            }
        }
#pragma unroll
        for (int s = 0; s < 2; s++) {
            bf16x8 af[4], bw[4];
#pragma unroll
            for (int i = 0; i < 4; i++) {
                int arow = wr * 64 + i * 16 + lr;
                af[i] = *(const bf16x8*)(Alds + arow * 64 + (((4 * s + lq) ^ (arow & 7)) << 3));
                int brow = wc * 64 + i * 16 + lr;
                bw[i] = *(const bf16x8*)(Blds + brow * 64 + (((4 * s + lq) ^ (brow & 7)) << 3));
            }
#pragma unroll
            for (int i = 0; i < 4; i++)
#pragma unroll
                for (int j = 0; j < 4; j++)
                    acc[i][j] = __builtin_amdgcn_mfma_f32_16x16x32_bf16(af[i], bw[j], acc[i][j], 0, 0, 0);
        }
    }
#pragma unroll
    for (int i = 0; i < 4; i++) {
#pragma unroll
        for (int j = 0; j < 4; j++) {
#pragma unroll
            for (int r = 0; r < 4; r++) {
                int gm = m0 + wr * 64 + i * 16 + lq * 4 + r;
                int gn = n0 + wc * 64 + j * 16 + lr;
                float val = acc[i][j][r] + bias[gn];
                if (EPI == 0) {
                    outb[(size_t)gm * N + gn] = f2bf(val);
                } else if (EPI == 1) {
                    float gl = 0.5f * val * (1.f + erff(val * 0.70710678118654752f));
                    outb[(size_t)gm * N + gn] = f2bf(gl);
                } else {
                    outf[(size_t)gm * N + gn] = res[(size_t)gm * N + gn] + ls[gn] * val;
                }
            }
        }
    }
}

// ---------------- V transpose: qkv_buf v-part -> Vt [B,H,D,T] ----------------
__global__ __launch_bounds__(256) void vtrans_kernel(const u16* __restrict__ qkv,
                                                     u16* __restrict__ vt) {
    __shared__ u16 tile[64 * 72];
    int t0 = blockIdx.x * 64, h = blockIdx.y, b = blockIdx.z;
    int tid = threadIdx.x;
#pragma unroll
    for (int i = 0; i < 2; i++) {
        int c = tid + i * 256, tr = c >> 3, j = c & 7;
        bf16x8 v = *(const bf16x8*)(qkv + (size_t)(b * T_ + t0 + tr) * N3C + 1536 + h * 64 + j * 8);
        *(bf16x8*)(tile + tr * 72 + j * 8) = v;
    }
    __syncthreads();
#pragma unroll
    for (int i = 0; i < 2; i++) {
        int c = tid + i * 256, d = c >> 3, tj = c & 7;
        bf16x8 o;
#pragma unroll
        for (int k = 0; k < 8; k++) o[k] = (short)tile[(tj * 8 + k) * 72 + d];
        *(bf16x8*)(vt + (size_t)((b * H_ + h) * 64 + d) * T_ + t0 + tj * 8) = o;
    }
}

// ---------------- fused attention, v6: qtile=8, deep counted-vmcnt DMA ----------------
// R7 lesson: vmcnt(0) = depth-1 pipeline (the T4 drain-0 anti-pattern). Now:
// 4 slots/wave, issue step n+3 then s_waitcnt vmcnt(6) -> 3 slots (6 KB) of
// bias+mask DMA in flight per wave, 48 KB/CU, zero VGPR cost. qtile=8 keeps
// S(32KB)+stage(32KB)=64KB -> 2 blocks/CU for cross-phase overlap.
__global__ __launch_bounds__(256, 2) void attn_kernel(const u16* __restrict__ qkv,
                                                      const u16* __restrict__ vt,
                                                      const float* __restrict__ bias,
                                                      const float* __restrict__ mask,
                                                      float* __restrict__ attn_out,
                                                      u16* __restrict__ ybuf) {
    __shared__ u16 S[8 * 2048];                      // 32KB bf16 logits -> bf16 P
    __shared__ __align__(16) float stg[4][4][2][256];  // 32KB [wave][slot][bias|mask][1KB]
    char* Sb = (char*)S;
    int qt = blockIdx.x, h = blockIdx.y, b = blockIdx.z;
    int tid = threadIdx.x, lane = tid & 63, wid = tid >> 6;
    int lr = lane & 15, lq = lane >> 4;
    int q0 = qt * 8;
    size_t bh = (size_t)(b * H_ + h);
    const float scale = 0.125f;

    // ---- A1: S = bf16(QK^T * scale), swapped mfma(K,Q); wave w owns cols w*512.. ----
    // Q operand rows duplicated (lr&7) so 8-row tile is safe; outputs for lr>=8 dropped.
    const u16* qp = qkv + (size_t)(b * T_ + q0 + (lr & 7)) * N3C + h * 64;
    bf16x8 qa0 = *(const bf16x8*)(qp + lq * 8);
    bf16x8 qa1 = *(const bf16x8*)(qp + 32 + lq * 8);
    const u16* kbase = qkv + (size_t)(b * T_ + wid * 512 + lr) * N3C + 768 + h * 64 + lq * 8;
#pragma unroll 4
    for (int ct = 0; ct < 32; ++ct) {
        bf16x8 kf0 = *(const bf16x8*)(kbase + (size_t)ct * 16 * N3C);
        bf16x8 kf1 = *(const bf16x8*)(kbase + (size_t)ct * 16 * N3C + 32);
        f32x4 a = (f32x4){0.f, 0.f, 0.f, 0.f};
        a = __builtin_amdgcn_mfma_f32_16x16x32_bf16(kf0, qa0, a, 0, 0, 0);
        a = __builtin_amdgcn_mfma_f32_16x16x32_bf16(kf1, qa1, a, 0, 0, 0);
        int colbase = wid * 512 + ct * 16;   // lane holds S[q-row=lr][colbase+lq*4 ..+3]
        if (lr < 8) {
            ushort4 pk;
            pk.x = f2bf(a[0] * scale);
            pk.y = f2bf(a[1] * scale);
            pk.z = f2bf(a[2] * scale);
            pk.w = f2bf(a[3] * scale);
            *(ushort4*)(Sb + (((u32)lr * 4096 + 2 * colbase + 8 * lq) ^ ((lr & 7) << 4))) = pk;
        }
    }
    __syncthreads();

    // ---- A2: P = exp(S + bias + mask); wave w owns rows 2w,2w+1; 16 steps of 1KB ----
    const float* bias_base = bias + (bh * T_ + q0 + wid * 2) * T_;
    const float* mask_base = mask + ((size_t)b * T_ + q0 + wid * 2) * T_;
    float lsum2[2] = {0.f, 0.f};

    // prologue: issue slots for steps 0,1,2 (strict step order for vmcnt counting)
#pragma unroll
    for (int s = 0; s < 3; ++s) {
        int rl = s >> 3, ch = s & 7;
        dma16(bias_base + (size_t)rl * T_ + ch * 256 + lane * 4, &stg[wid][s & 3][0][0]);
        dma16(mask_base + (size_t)rl * T_ + ch * 256 + lane * 4, &stg[wid][s & 3][1][0]);
    }

#pragma unroll 1
    for (int step = 0; step < 16; ++step) {
        if (step + 3 < 16) {
            int ns = step + 3, rl = ns >> 3, ch = ns & 7;
            dma16(bias_base + (size_t)rl * T_ + ch * 256 + lane * 4, &stg[wid][ns & 3][0][0]);
            dma16(mask_base + (size_t)rl * T_ + ch * 256 + lane * 4, &stg[wid][ns & 3][1][0]);
        }
        if (step < 13)      asm volatile("s_waitcnt vmcnt(6)" ::: "memory");
        else if (step == 13) asm volatile("s_waitcnt vmcnt(4)" ::: "memory");
        else if (step == 14) asm volatile("s_waitcnt vmcnt(2)" ::: "memory");
        else                 asm volatile("s_waitcnt vmcnt(0)" ::: "memory");
        __builtin_amdgcn_sched_barrier(0);

        int rl = step >> 3, ch = step & 7;
        int r = wid * 2 + rl;
        int col = ch * 256 + lane * 4;
        float4 bv = *(const float4*)&stg[wid][step & 3][0][lane * 4];
        float4 mv = *(const float4*)&stg[wid][step & 3][1][lane * 4];
        u32 addr = ((u32)r * 4096 + (u32)col * 2) ^ ((u32)(r & 7) << 4);
        uint2 s2 = *(const uint2*)(Sb + addr);
        float e0 = __expf(__uint_as_float(s2.x << 16) + bv.x + mv.x);
        float e1 = __expf(__uint_as_float(s2.x & 0xffff0000u) + bv.y + mv.y);
        float e2 = __expf(__uint_as_float(s2.y << 16) + bv.z + mv.z);
        float e3 = __expf(__uint_as_float(s2.y & 0xffff0000u) + bv.w + mv.w);
        lsum2[rl] += (e0 + e1) + (e2 + e3);
        uint2 o;
        o.x = ((u32)f2bf(e1) << 16) | (u32)f2bf(e0);
        o.y = ((u32)f2bf(e3) << 16) | (u32)f2bf(e2);
        *(uint2*)(Sb + addr) = o;                    // in-place bf16 P
    }
    // row sums -> rinv; park in this wave's (now dead) slot-0 stage buffer
    float rinv_r[2];
#pragma unroll
    for (int rr = 0; rr < 2; ++rr) {
        float ls = lsum2[rr];
        for (int m = 32; m; m >>= 1) ls += __shfl_xor(ls, m);
        rinv_r[rr] = 1.f / ls;
        if (lane == 0) stg[wid][0][0][rr] = rinv_r[rr];
    }
    __syncthreads();

    // ---- A3: attn_out = P * rinv, contiguous float4 stores ----
    float* ao_base = attn_out + (bh * T_ + q0 + wid * 2) * T_;
#pragma unroll
    for (int ch = 0; ch < 8; ++ch) {
        int col = ch * 256 + lane * 4;
#pragma unroll
        for (int rr = 0; rr < 2; ++rr) {
            int r = wid * 2 + rr;
            u32 addr = ((u32)r * 4096 + (u32)col * 2) ^ ((u32)(r & 7) << 4);
            uint2 s2 = *(const uint2*)(Sb + addr);
            float rv = rinv_r[rr];
            float4 o;
            o.x = __uint_as_float(s2.x << 16) * rv;
            o.y = __uint_as_float(s2.x & 0xffff0000u) * rv;
            o.z = __uint_as_float(s2.y << 16) * rv;
            o.w = __uint_as_float(s2.y & 0xffff0000u) * rv;
            *(float4*)(ao_base + (size_t)rr * T_ + col) = o;
        }
    }

    // ---- C: y = (P @ V) * rinv; wave w owns d-cols 16w..16w+15 ----
    f32x4 acc = (f32x4){0.f, 0.f, 0.f, 0.f};
    const u16* vtp = vt + (bh * 64 + wid * 16 + lr) * (size_t)T_ + lq * 8;
#pragma unroll 4
    for (int ks = 0; ks < 64; ++ks) {
        // P operand rows duplicated via lr&7 (outputs for q-rows >=8 discarded)
        bf16x8 pf = *(const bf16x8*)(Sb + (((u32)(lr & 7) * 4096 + ks * 64 + lq * 16) ^ ((u32)(lr & 7) << 4)));
        bf16x8 vf = *(const bf16x8*)(vtp + ks * 32);
        acc = __builtin_amdgcn_mfma_f32_16x16x32_bf16(pf, vf, acc, 0, 0, 0);
    }
#pragma unroll
    for (int r = 0; r < 4; r++) {
        int row = lq * 4 + r;
        if (row < 8) {
            float y = acc[r] * stg[row >> 1][0][0][row & 1];
            ybuf[(size_t)(b * T_ + q0 + row) * C_ + h * 64 + wid * 16 + lr] = f2bf(y);
        }
    }
}

// ---------------- host ----------------
extern "C" void kernel_launch(void* const* d_in, const int* in_sizes, int n_in,
                              void* d_out, int out_size, void* d_ws, size_t ws_size,
                              hipStream_t stream) {
    const float* x = (const float*)d_in[0];
    const float* mask = (const float*)d_in[1];
    const float* bias = (const float*)d_in[2];
    const float* ln1g = (const float*)d_in[3];
    const float* ln1b = (const float*)d_in[4];
    const float* qkvw = (const float*)d_in[5];
    const float* qkvb = (const float*)d_in[6];
    const float* projw = (const float*)d_in[7];
    const float* projb = (const float*)d_in[8];
    const float* ls1 = (const float*)d_in[9];
    const float* ln2g = (const float*)d_in[10];
    const float* ln2b = (const float*)d_in[11];
    const float* w1 = (const float*)d_in[12];
    const float* b1 = (const float*)d_in[13];
    const float* w2 = (const float*)d_in[14];
    const float* b2 = (const float*)d_in[15];
    const float* ls2 = (const float*)d_in[16];

    char* ws = (char*)d_ws;
    size_t off = 0;
    u16* qkvw_b = (u16*)(ws + off); off += (size_t)N3C * C_ * 2;
    u16* projw_b = (u16*)(ws + off); off += (size_t)C_ * C_ * 2;
    u16* w1_b = (u16*)(ws + off); off += (size_t)HID_ * C_ * 2;
    u16* w2_b = (u16*)(ws + off); off += (size_t)C_ * HID_ * 2;
    u16* xn = (u16*)(ws + off); off += (size_t)NROW * C_ * 2;          // reused as hn after attn
    u16* qkvbuf = (u16*)(ws + off); off += (size_t)NROW * N3C * 2;     // } contiguous; reused as
    u16* vt = (u16*)(ws + off); off += (size_t)B_ * H_ * D_ * T_ * 2;  // } g [4096,3072] after attn
    u16* g = qkvbuf;
    u16* ybuf = (u16*)(ws + off); off += (size_t)NROW * C_ * 2;
    float* x1 = (float*)(ws + off); off += (size_t)NROW * C_ * 4;
    (void)ws_size; (void)n_in; (void)in_sizes; (void)out_size;

    float* outx = (float*)d_out;
    float* attn_out = outx + (size_t)NROW * C_;

    // weights -> bf16
    cvt_bf16_kernel<<<(N3C * C_ / 4 + 255) / 256, 256, 0, stream>>>(qkvw, qkvw_b, N3C * C_);
    cvt_bf16_kernel<<<(C_ * C_ / 4 + 255) / 256, 256, 0, stream>>>(projw, projw_b, C_ * C_);
    cvt_bf16_kernel<<<(HID_ * C_ / 4 + 255) / 256, 256, 0, stream>>>(w1, w1_b, HID_ * C_);
    cvt_bf16_kernel<<<(C_ * HID_ / 4 + 255) / 256, 256, 0, stream>>>(w2, w2_b, C_ * HID_);

    // LN1
    ln_kernel<<<NROW, 256, 0, stream>>>(x, ln1g, ln1b, xn);
    // QKV
    gemm_kernel<0><<<dim3(N3C / 128, NROW / 128), 256, 0, stream>>>(
        xn, qkvw_b, qkvb, nullptr, qkvbuf, nullptr, nullptr, N3C, C_);
    // V transpose
    vtrans_kernel<<<dim3(T_ / 64, H_, B_), 256, 0, stream>>>(qkvbuf, vt);
    // fused attention (qtile = 8)
    attn_kernel<<<dim3(T_ / 8, H_, B_), 256, 0, stream>>>(qkvbuf, vt, bias, mask, attn_out, ybuf);
    // proj + residual*ls1 -> x1
    gemm_kernel<2><<<dim3(C_ / 128, NROW / 128), 256, 0, stream>>>(
        ybuf, projw_b, projb, x1, nullptr, x, ls1, C_, C_);
    // LN2
    ln_kernel<<<NROW, 256, 0, stream>>>(x1, ln2g, ln2b, xn);
    // MLP1 + gelu
    gemm_kernel<1><<<dim3(HID_ / 128, NROW / 128), 256, 0, stream>>>(
        xn, w1_b, b1, nullptr, g, nullptr, nullptr, HID_, C_);
    // MLP2 + residual*ls2 -> out
    gemm_kernel<2><<<dim3(C_ / 128, NROW / 128), 256, 0, stream>>>(
        g, w2_b, b2, outx, nullptr, x1, ls2, C_, HID_);
}

// Round 9
// 542.240 us; speedup vs baseline: 1.3847x; 1.3847x over previous
//
#include <hip/hip_runtime.h>
#include <hip/hip_bf16.h>
#include <math.h>

#define B_ 2
#define T_ 2048
#define C_ 768
#define H_ 12
#define D_ 64
#define HID_ 3072
#define NROW 4096   // B*T
#define N3C 2304    // 3*C

typedef short bf16x8 __attribute__((ext_vector_type(8)));
typedef float f32x4 __attribute__((ext_vector_type(4)));
typedef unsigned short u16;
typedef unsigned int u32;

__device__ inline u16 f2bf(float f) {
    u32 u = __float_as_uint(f);
    u32 r = (u + 0x7fffu + ((u >> 16) & 1u)) >> 16;  // RNE
    return (u16)r;
}

__device__ __forceinline__ void dma16(const float* g, float* lds) {
    // each lane: 16B from its g -> ldsbase + lane*16 (linear, wave-uniform base)
    __builtin_amdgcn_global_load_lds(
        (const __attribute__((address_space(1))) void*)g,
        (__attribute__((address_space(3))) void*)lds, 16, 0, 0);
}

// ---------------- weight / activation f32 -> bf16 convert ----------------
__global__ __launch_bounds__(256) void cvt_bf16_kernel(const float* __restrict__ s,
                                                       u16* __restrict__ d, int n) {
    int i = (blockIdx.x * 256 + threadIdx.x) * 4;
    if (i >= n) return;
    float4 v = *(const float4*)(s + i);
    ushort4 o;
    o.x = f2bf(v.x); o.y = f2bf(v.y); o.z = f2bf(v.z); o.w = f2bf(v.w);
    *(ushort4*)(d + i) = o;
}

// ---------------- LayerNorm (f32 in, bf16 out), one block per row ----------------
__global__ __launch_bounds__(256) void ln_kernel(const float* __restrict__ x,
                                                 const float* __restrict__ g,
                                                 const float* __restrict__ b,
                                                 u16* __restrict__ out) {
    int row = blockIdx.x, t = threadIdx.x;
    const float* xr = x + (size_t)row * C_;
    float v[3], s = 0.f, sq = 0.f;
#pragma unroll
    for (int i = 0; i < 3; i++) {
        v[i] = xr[i * 256 + t];
        s += v[i]; sq += v[i] * v[i];
    }
    for (int m = 32; m; m >>= 1) { s += __shfl_xor(s, m); sq += __shfl_xor(sq, m); }
    __shared__ float ss[4], ssq[4];
    int wid = t >> 6;
    if ((t & 63) == 0) { ss[wid] = s; ssq[wid] = sq; }
    __syncthreads();
    s = ss[0] + ss[1] + ss[2] + ss[3];
    sq = ssq[0] + ssq[1] + ssq[2] + ssq[3];
    float mu = s * (1.f / C_);
    float var = sq * (1.f / C_) - mu * mu;
    float rstd = rsqrtf(var + 1e-5f);
#pragma unroll
    for (int i = 0; i < 3; i++) {
        int c = i * 256 + t;
        out[(size_t)row * C_ + c] = f2bf((v[i] - mu) * rstd * g[c] + b[c]);
    }
}

// ---------------- bf16 MFMA GEMM: out = A[M,K] @ W[N,K]^T (+bias, epilogues) ----------------
template <int EPI>
__global__ __launch_bounds__(256) void gemm_kernel(const u16* __restrict__ A,
                                                   const u16* __restrict__ W,
                                                   const float* __restrict__ bias,
                                                   float* __restrict__ outf,
                                                   u16* __restrict__ outb,
                                                   const float* __restrict__ res,
                                                   const float* __restrict__ ls,
                                                   int N, int K) {
    __shared__ u16 Alds[128 * 64];
    __shared__ u16 Blds[128 * 64];
    int tid = threadIdx.x;
    int m0 = blockIdx.y * 128, n0 = blockIdx.x * 128;
    int lane = tid & 63, wid = tid >> 6;
    int wr = wid >> 1, wc = wid & 1;
    int lr = lane & 15, lq = lane >> 4;

    f32x4 acc[4][4];
#pragma unroll
    for (int i = 0; i < 4; i++)
#pragma unroll
        for (int j = 0; j < 4; j++) acc[i][j] = (f32x4){0.f, 0.f, 0.f, 0.f};

    int nk = K >> 6;
    const u16* Ab = A + (size_t)m0 * K;
    const u16* Wb = W + (size_t)n0 * K;
    bf16x8 ra[4], rb[4];
#pragma unroll
    for (int i = 0; i < 4; i++) {
        int c = tid + i * 256, row = c >> 3, j = c & 7;
        ra[i] = *(const bf16x8*)(Ab + (size_t)row * K + j * 8);
        rb[i] = *(const bf16x8*)(Wb + (size_t)row * K + j * 8);
    }
    for (int kt = 0; kt < nk; ++kt) {
        __syncthreads();
#pragma unroll
        for (int i = 0; i < 4; i++) {
            int c = tid + i * 256, row = c >> 3, j = c & 7;
            int off = row * 64 + ((j ^ (row & 7)) << 3);   // XOR-swizzled 16B blocks
            *(bf16x8*)(Alds + off) = ra[i];
            *(bf16x8*)(Blds + off) = rb[i];
        }
        __syncthreads();
        if (kt + 1 < nk) {
            int k0 = (kt + 1) << 6;
#pragma unroll
            for (int i = 0; i < 4; i++) {
                int c = tid + i * 256, row = c >> 3, j = c & 7;
                ra[i] = *(const bf16x8*)(Ab + (size_t)row * K + k0 + j * 8);
                rb[i] = *(const bf16x8*)(Wb + (size_t)row * K + k0 + j * 8);
            }
        }
#pragma unroll
        for (int s = 0; s < 2; s++) {
            bf16x8 af[4], bw[4];
#pragma unroll
            for (int i = 0; i < 4; i++) {
                int arow = wr * 64 + i * 16 + lr;
                af[i] = *(const bf16x8*)(Alds + arow * 64 + (((4 * s + lq) ^ (arow & 7)) << 3));
                int brow = wc * 64 + i * 16 + lr;
                bw[i] = *(const bf16x8*)(Blds + brow * 64 + (((4 * s + lq) ^ (brow & 7)) << 3));
            }
#pragma unroll
            for (int i = 0; i < 4; i++)
#pragma unroll
                for (int j = 0; j < 4; j++)
                    acc[i][j] = __builtin_amdgcn_mfma_f32_16x16x32_bf16(af[i], bw[j], acc[i][j], 0, 0, 0);
        }
    }
#pragma unroll
    for (int i = 0; i < 4; i++) {
#pragma unroll
        for (int j = 0; j < 4; j++) {
#pragma unroll
            for (int r = 0; r < 4; r++) {
                int gm = m0 + wr * 64 + i * 16 + lq * 4 + r;
                int gn = n0 + wc * 64 + j * 16 + lr;
                float val = acc[i][j][r] + bias[gn];
                if (EPI == 0) {
                    outb[(size_t)gm * N + gn] = f2bf(val);
                } else if (EPI == 1) {
                    float gl = 0.5f * val * (1.f + erff(val * 0.70710678118654752f));
                    outb[(size_t)gm * N + gn] = f2bf(gl);
                } else {
                    outf[(size_t)gm * N + gn] = res[(size_t)gm * N + gn] + ls[gn] * val;
                }
            }
        }
    }
}

// ---------------- V transpose: qkv_buf v-part -> Vt [B,H,D,T] ----------------
__global__ __launch_bounds__(256) void vtrans_kernel(const u16* __restrict__ qkv,
                                                     u16* __restrict__ vt) {
    __shared__ u16 tile[64 * 72];
    int t0 = blockIdx.x * 64, h = blockIdx.y, b = blockIdx.z;
    int tid = threadIdx.x;
#pragma unroll
    for (int i = 0; i < 2; i++) {
        int c = tid + i * 256, tr = c >> 3, j = c & 7;
        bf16x8 v = *(const bf16x8*)(qkv + (size_t)(b * T_ + t0 + tr) * N3C + 1536 + h * 64 + j * 8);
        *(bf16x8*)(tile + tr * 72 + j * 8) = v;
    }
    __syncthreads();
#pragma unroll
    for (int i = 0; i < 2; i++) {
        int c = tid + i * 256, d = c >> 3, tj = c & 7;
        bf16x8 o;
#pragma unroll
        for (int k = 0; k < 8; k++) o[k] = (short)tile[(tj * 8 + k) * 72 + d];
        *(bf16x8*)(vt + (size_t)((b * H_ + h) * 64 + d) * T_ + t0 + tj * 8) = o;
    }
}

// ---- A2 step: bias DMA pipeline (4 slots, depth 3), pure single VMEM stream ----
template <int WAITN, bool ISSUE>
__device__ __forceinline__ void a2_step(int row, int ch, float& ls,
                                        const float* bias_base, char* Sb,
                                        float (*stgw)[256], int lane, int r) {
    int step = row * 8 + ch;
    if (ISSUE) {
        int ns = step + 3;
        dma16(bias_base + (size_t)(ns >> 3) * T_ + (ns & 7) * 256 + lane * 4,
              &stgw[ns & 3][0]);
    }
    if constexpr (WAITN == 3) asm volatile("s_waitcnt vmcnt(3)" ::: "memory");
    else if constexpr (WAITN == 2) asm volatile("s_waitcnt vmcnt(2)" ::: "memory");
    else if constexpr (WAITN == 1) asm volatile("s_waitcnt vmcnt(1)" ::: "memory");
    else asm volatile("s_waitcnt vmcnt(0)" ::: "memory");
    __builtin_amdgcn_sched_barrier(0);
    int col = ch * 256 + lane * 4;
    float4 bv = *(const float4*)&stgw[step & 3][lane * 4];
    u32 addr = ((u32)r * 4096 + (u32)col * 2) ^ ((u32)(r & 7) << 4);
    uint2 s2 = *(const uint2*)(Sb + addr);
    float e0 = __expf(__uint_as_float(s2.x << 16) + bv.x);
    float e1 = __expf(__uint_as_float(s2.x & 0xffff0000u) + bv.y);
    float e2 = __expf(__uint_as_float(s2.y << 16) + bv.z);
    float e3 = __expf(__uint_as_float(s2.y & 0xffff0000u) + bv.w);
    ls += (e0 + e1) + (e2 + e3);
    uint2 o;
    o.x = ((u32)f2bf(e1) << 16) | (u32)f2bf(e0);
    o.y = ((u32)f2bf(e3) << 16) | (u32)f2bf(e2);
    *(uint2*)(Sb + addr) = o;                // in-place bf16 P
}

// ---------------- fused attention, v7: qtile=16, mask folded into A1, ----------------
// A2 = pure bias-DMA pipeline with counted vmcnt (the un-confounded deep-pipeline test).
__global__ __launch_bounds__(256, 2) void attn_kernel(const u16* __restrict__ qkv,
                                                      const u16* __restrict__ vt,
                                                      const float* __restrict__ bias,
                                                      const float* __restrict__ mask,
                                                      float* __restrict__ attn_out,
                                                      u16* __restrict__ ybuf) {
    __shared__ u16 S[16 * 2048];                       // 64KB bf16 (S+mask) -> bf16 P
    __shared__ __align__(16) float stg[4][4][256];     // 16KB bias stage: [wave][slot][1KB]
    char* Sb = (char*)S;
    int qt = blockIdx.x, h = blockIdx.y, b = blockIdx.z;
    int tid = threadIdx.x, lane = tid & 63, wid = tid >> 6;
    int lr = lane & 15, lq = lane >> 4;
    int q0 = qt * 16;
    size_t bh = (size_t)(b * H_ + h);
    const float scale = 0.125f;

    // ---- A1: S = bf16(QK^T*scale + mask); mask is L3-resident (34MB, head-broadcast) ----
    const u16* qp = qkv + (size_t)(b * T_ + q0 + lr) * N3C + h * 64;
    bf16x8 qa0 = *(const bf16x8*)(qp + lq * 8);
    bf16x8 qa1 = *(const bf16x8*)(qp + 32 + lq * 8);
    const u16* kbase = qkv + (size_t)(b * T_ + wid * 512 + lr) * N3C + 768 + h * 64 + lq * 8;
    const float* mbase = mask + ((size_t)b * T_ + q0 + lr) * T_ + wid * 512 + lq * 4;
#pragma unroll 4
    for (int ct = 0; ct < 32; ++ct) {
        bf16x8 kf0 = *(const bf16x8*)(kbase + (size_t)ct * 16 * N3C);
        bf16x8 kf1 = *(const bf16x8*)(kbase + (size_t)ct * 16 * N3C + 32);
        float4 mv = *(const float4*)(mbase + ct * 16);
        f32x4 a = (f32x4){0.f, 0.f, 0.f, 0.f};
        a = __builtin_amdgcn_mfma_f32_16x16x32_bf16(kf0, qa0, a, 0, 0, 0);
        a = __builtin_amdgcn_mfma_f32_16x16x32_bf16(kf1, qa1, a, 0, 0, 0);
        int colbase = wid * 512 + ct * 16;   // lane holds S[lr][colbase+lq*4 ..+3]
        ushort4 pk;
        pk.x = f2bf(a[0] * scale + mv.x);
        pk.y = f2bf(a[1] * scale + mv.y);
        pk.z = f2bf(a[2] * scale + mv.z);
        pk.w = f2bf(a[3] * scale + mv.w);
        *(ushort4*)(Sb + (((u32)lr * 4096 + 2 * colbase + 8 * lq) ^ ((lr & 7) << 4))) = pk;
    }
    __syncthreads();   // drains vmcnt to 0 -> clean slate for the DMA pipeline

    // ---- A2: P = exp(S + bias); wave w owns rows 4w..4w+3; 32 steps of 1KB bias DMA ----
    const float* bias_base = bias + (bh * T_ + q0 + wid * 4) * T_;
    float lsum4[4] = {0.f, 0.f, 0.f, 0.f};
    // prologue: slots for steps 0,1,2 (row 0, chunks 0..2)
#pragma unroll
    for (int s = 0; s < 3; ++s)
        dma16(bias_base + s * 256 + lane * 4, &stg[wid][s][0]);
#pragma unroll
    for (int row = 0; row < 4; ++row) {
        int r = wid * 4 + row;
        if (row < 3) {
#pragma unroll 1
            for (int ch = 0; ch < 8; ++ch)
                a2_step<3, true>(row, ch, lsum4[row], bias_base, Sb, stg[wid], lane, r);
        } else {
#pragma unroll 1
            for (int ch = 0; ch < 5; ++ch)
                a2_step<3, true>(3, ch, lsum4[3], bias_base, Sb, stg[wid], lane, r);
            a2_step<2, false>(3, 5, lsum4[3], bias_base, Sb, stg[wid], lane, r);
            a2_step<1, false>(3, 6, lsum4[3], bias_base, Sb, stg[wid], lane, r);
            a2_step<0, false>(3, 7, lsum4[3], bias_base, Sb, stg[wid], lane, r);
        }
    }
    // row sums -> rinv; park in this wave's (dead) slot 0 for phase C cross-wave reads
    float rinv_r[4];
#pragma unroll
    for (int rr = 0; rr < 4; ++rr) {
        float ls = lsum4[rr];
        for (int m = 32; m; m >>= 1) ls += __shfl_xor(ls, m);
        rinv_r[rr] = 1.f / ls;
        if (lane == 0) stg[wid][0][rr] = rinv_r[rr];
    }
    __syncthreads();

    // ---- A3: attn_out = P * rinv, 4 rows batched, contiguous float4 stores ----
    float* ao_base = attn_out + (bh * T_ + q0 + wid * 4) * T_;
#pragma unroll
    for (int ch = 0; ch < 8; ++ch) {
        int col = ch * 256 + lane * 4;
#pragma unroll
        for (int rr = 0; rr < 4; ++rr) {
            int r = wid * 4 + rr;
            u32 addr = ((u32)r * 4096 + (u32)col * 2) ^ ((u32)(r & 7) << 4);
            uint2 s2 = *(const uint2*)(Sb + addr);
            float rv = rinv_r[rr];
            float4 o;
            o.x = __uint_as_float(s2.x << 16) * rv;
            o.y = __uint_as_float(s2.x & 0xffff0000u) * rv;
            o.z = __uint_as_float(s2.y << 16) * rv;
            o.w = __uint_as_float(s2.y & 0xffff0000u) * rv;
            *(float4*)(ao_base + (size_t)rr * T_ + col) = o;
        }
    }

    // ---- C: y = (P @ V) * rinv; wave w owns d-cols 16w..16w+15 ----
    f32x4 acc = (f32x4){0.f, 0.f, 0.f, 0.f};
    const u16* vtp = vt + (bh * 64 + wid * 16 + lr) * (size_t)T_ + lq * 8;
#pragma unroll 4
    for (int ks = 0; ks < 64; ++ks) {
        bf16x8 pf = *(const bf16x8*)(Sb + (((u32)lr * 4096 + ks * 64 + lq * 16) ^ ((lr & 7) << 4)));
        bf16x8 vf = *(const bf16x8*)(vtp + ks * 32);
        acc = __builtin_amdgcn_mfma_f32_16x16x32_bf16(pf, vf, acc, 0, 0, 0);
    }
#pragma unroll
    for (int r = 0; r < 4; r++) {
        int row = lq * 4 + r;
        float y = acc[r] * stg[row >> 2][0][row & 3];
        ybuf[(size_t)(b * T_ + q0 + row) * C_ + h * 64 + wid * 16 + lr] = f2bf(y);
    }
}

// ---------------- host ----------------
extern "C" void kernel_launch(void* const* d_in, const int* in_sizes, int n_in,
                              void* d_out, int out_size, void* d_ws, size_t ws_size,
                              hipStream_t stream) {
    const float* x = (const float*)d_in[0];
    const float* mask = (const float*)d_in[1];
    const float* bias = (const float*)d_in[2];
    const float* ln1g = (const float*)d_in[3];
    const float* ln1b = (const float*)d_in[4];
    const float* qkvw = (const float*)d_in[5];
    const float* qkvb = (const float*)d_in[6];
    const float* projw = (const float*)d_in[7];
    const float* projb = (const float*)d_in[8];
    const float* ls1 = (const float*)d_in[9];
    const float* ln2g = (const float*)d_in[10];
    const float* ln2b = (const float*)d_in[11];
    const float* w1 = (const float*)d_in[12];
    const float* b1 = (const float*)d_in[13];
    const float* w2 = (const float*)d_in[14];
    const float* b2 = (const float*)d_in[15];
    const float* ls2 = (const float*)d_in[16];

    char* ws = (char*)d_ws;
    size_t off = 0;
    u16* qkvw_b = (u16*)(ws + off); off += (size_t)N3C * C_ * 2;
    u16* projw_b = (u16*)(ws + off); off += (size_t)C_ * C_ * 2;
    u16* w1_b = (u16*)(ws + off); off += (size_t)HID_ * C_ * 2;
    u16* w2_b = (u16*)(ws + off); off += (size_t)C_ * HID_ * 2;
    u16* xn = (u16*)(ws + off); off += (size_t)NROW * C_ * 2;          // reused as hn after attn
    u16* qkvbuf = (u16*)(ws + off); off += (size_t)NROW * N3C * 2;     // } contiguous; reused as
    u16* vt = (u16*)(ws + off); off += (size_t)B_ * H_ * D_ * T_ * 2;  // } g [4096,3072] after attn
    u16* g = qkvbuf;
    u16* ybuf = (u16*)(ws + off); off += (size_t)NROW * C_ * 2;
    float* x1 = (float*)(ws + off); off += (size_t)NROW * C_ * 4;
    (void)ws_size; (void)n_in; (void)in_sizes; (void)out_size;

    float* outx = (float*)d_out;
    float* attn_out = outx + (size_t)NROW * C_;

    // weights -> bf16
    cvt_bf16_kernel<<<(N3C * C_ / 4 + 255) / 256, 256, 0, stream>>>(qkvw, qkvw_b, N3C * C_);
    cvt_bf16_kernel<<<(C_ * C_ / 4 + 255) / 256, 256, 0, stream>>>(projw, projw_b, C_ * C_);
    cvt_bf16_kernel<<<(HID_ * C_ / 4 + 255) / 256, 256, 0, stream>>>(w1, w1_b, HID_ * C_);
    cvt_bf16_kernel<<<(C_ * HID_ / 4 + 255) / 256, 256, 0, stream>>>(w2, w2_b, C_ * HID_);

    // LN1
    ln_kernel<<<NROW, 256, 0, stream>>>(x, ln1g, ln1b, xn);
    // QKV
    gemm_kernel<0><<<dim3(N3C / 128, NROW / 128), 256, 0, stream>>>(
        xn, qkvw_b, qkvb, nullptr, qkvbuf, nullptr, nullptr, N3C, C_);
    // V transpose
    vtrans_kernel<<<dim3(T_ / 64, H_, B_), 256, 0, stream>>>(qkvbuf, vt);
    // fused attention (qtile = 16)
    attn_kernel<<<dim3(T_ / 16, H_, B_), 256, 0, stream>>>(qkvbuf, vt, bias, mask, attn_out, ybuf);
    // proj + residual*ls1 -> x1
    gemm_kernel<2><<<dim3(C_ / 128, NROW / 128), 256, 0, stream>>>(
        ybuf, projw_b, projb, x1, nullptr, x, ls1, C_, C_);
    // LN2
    ln_kernel<<<NROW, 256, 0, stream>>>(x1, ln2g, ln2b, xn);
    // MLP1 + gelu
    gemm_kernel<1><<<dim3(HID_ / 128, NROW / 128), 256, 0, stream>>>(
        xn, w1_b, b1, nullptr, g, nullptr, nullptr, HID_, C_);
    // MLP2 + residual*ls2 -> out
    gemm_kernel<2><<<dim3(C_ / 128, NROW / 128), 256, 0, stream>>>(
        g, w2_b, b2, outx, nullptr, x1, ls2, C_, HID_);
}

// Round 10
// 436.619 us; speedup vs baseline: 1.7196x; 1.2419x over previous
//
#include <hip/hip_runtime.h>
#include <hip/hip_bf16.h>
#include <math.h>

#define B_ 2
#define T_ 2048
#define C_ 768
#define H_ 12
#define D_ 64
#define HID_ 3072
#define NROW 4096   // B*T
#define N3C 2304    // 3*C

typedef short bf16x8 __attribute__((ext_vector_type(8)));
typedef float f32x4 __attribute__((ext_vector_type(4)));
typedef unsigned short u16;
typedef unsigned int u32;

__device__ inline u16 f2bf(float f) {
    u32 u = __float_as_uint(f);
    u32 r = (u + 0x7fffu + ((u >> 16) & 1u)) >> 16;  // RNE
    return (u16)r;
}

// ---------------- weight / activation f32 -> bf16 convert ----------------
__global__ __launch_bounds__(256) void cvt_bf16_kernel(const float* __restrict__ s,
                                                       u16* __restrict__ d, int n) {
    int i = (blockIdx.x * 256 + threadIdx.x) * 4;
    if (i >= n) return;
    float4 v = *(const float4*)(s + i);
    ushort4 o;
    o.x = f2bf(v.x); o.y = f2bf(v.y); o.z = f2bf(v.z); o.w = f2bf(v.w);
    *(ushort4*)(d + i) = o;
}

// ---------------- LayerNorm (f32 in, bf16 out), one block per row ----------------
__global__ __launch_bounds__(256) void ln_kernel(const float* __restrict__ x,
                                                 const float* __restrict__ g,
                                                 const float* __restrict__ b,
                                                 u16* __restrict__ out) {
    int row = blockIdx.x, t = threadIdx.x;
    const float* xr = x + (size_t)row * C_;
    float v[3], s = 0.f, sq = 0.f;
#pragma unroll
    for (int i = 0; i < 3; i++) {
        v[i] = xr[i * 256 + t];
        s += v[i]; sq += v[i] * v[i];
    }
    for (int m = 32; m; m >>= 1) { s += __shfl_xor(s, m); sq += __shfl_xor(sq, m); }
    __shared__ float ss[4], ssq[4];
    int wid = t >> 6;
    if ((t & 63) == 0) { ss[wid] = s; ssq[wid] = sq; }
    __syncthreads();
    s = ss[0] + ss[1] + ss[2] + ss[3];
    sq = ssq[0] + ssq[1] + ssq[2] + ssq[3];
    float mu = s * (1.f / C_);
    float var = sq * (1.f / C_) - mu * mu;
    float rstd = rsqrtf(var + 1e-5f);
#pragma unroll
    for (int i = 0; i < 3; i++) {
        int c = i * 256 + t;
        out[(size_t)row * C_ + c] = f2bf((v[i] - mu) * rstd * g[c] + b[c]);
    }
}

// ---------------- bf16 MFMA GEMM: out = A[M,K] @ W[N,K]^T (+bias, epilogues) ----------------
template <int EPI>
__global__ __launch_bounds__(256) void gemm_kernel(const u16* __restrict__ A,
                                                   const u16* __restrict__ W,
                                                   const float* __restrict__ bias,
                                                   float* __restrict__ outf,
                                                   u16* __restrict__ outb,
                                                   const float* __restrict__ res,
                                                   const float* __restrict__ ls,
                                                   int N, int K) {
    __shared__ u16 Alds[128 * 64];
    __shared__ u16 Blds[128 * 64];
    int tid = threadIdx.x;
    int m0 = blockIdx.y * 128, n0 = blockIdx.x * 128;
    int lane = tid & 63, wid = tid >> 6;
    int wr = wid >> 1, wc = wid & 1;
    int lr = lane & 15, lq = lane >> 4;

    f32x4 acc[4][4];
#pragma unroll
    for (int i = 0; i < 4; i++)
#pragma unroll
        for (int j = 0; j < 4; j++) acc[i][j] = (f32x4){0.f, 0.f, 0.f, 0.f};

    int nk = K >> 6;
    const u16* Ab = A + (size_t)m0 * K;
    const u16* Wb = W + (size_t)n0 * K;
    bf16x8 ra[4], rb[4];
#pragma unroll
    for (int i = 0; i < 4; i++) {
        int c = tid + i * 256, row = c >> 3, j = c & 7;
        ra[i] = *(const bf16x8*)(Ab + (size_t)row * K + j * 8);
        rb[i] = *(const bf16x8*)(Wb + (size_t)row * K + j * 8);
    }
    for (int kt = 0; kt < nk; ++kt) {
        __syncthreads();
#pragma unroll
        for (int i = 0; i < 4; i++) {
            int c = tid + i * 256, row = c >> 3, j = c & 7;
            int off = row * 64 + ((j ^ (row & 7)) << 3);   // XOR-swizzled 16B blocks
            *(bf16x8*)(Alds + off) = ra[i];
            *(bf16x8*)(Blds + off) = rb[i];
        }
        __syncthreads();
        if (kt + 1 < nk) {
            int k0 = (kt + 1) << 6;
#pragma unroll
            for (int i = 0; i < 4; i++) {
                int c = tid + i * 256, row = c >> 3, j = c & 7;
                ra[i] = *(const bf16x8*)(Ab + (size_t)row * K + k0 + j * 8);
                rb[i] = *(const bf16x8*)(Wb + (size_t)row * K + k0 + j * 8);
            }
        }
#pragma unroll
        for (int s = 0; s < 2; s++) {
            bf16x8 af[4], bw[4];
#pragma unroll
            for (int i = 0; i < 4; i++) {
                int arow = wr * 64 + i * 16 + lr;
                af[i] = *(const bf16x8*)(Alds + arow * 64 + (((4 * s + lq) ^ (arow & 7)) << 3));
                int brow = wc * 64 + i * 16 + lr;
                bw[i] = *(const bf16x8*)(Blds + brow * 64 + (((4 * s + lq) ^ (brow & 7)) << 3));
            }
#pragma unroll
            for (int i = 0; i < 4; i++)
#pragma unroll
                for (int j = 0; j < 4; j++)
                    acc[i][j] = __builtin_amdgcn_mfma_f32_16x16x32_bf16(af[i], bw[j], acc[i][j], 0, 0, 0);
        }
    }
#pragma unroll
    for (int i = 0; i < 4; i++) {
#pragma unroll
        for (int j = 0; j < 4; j++) {
#pragma unroll
            for (int r = 0; r < 4; r++) {
                int gm = m0 + wr * 64 + i * 16 + lq * 4 + r;
                int gn = n0 + wc * 64 + j * 16 + lr;
                float val = acc[i][j][r] + bias[gn];
                if (EPI == 0) {
                    outb[(size_t)gm * N + gn] = f2bf(val);
                } else if (EPI == 1) {
                    float gl = 0.5f * val * (1.f + erff(val * 0.70710678118654752f));
                    outb[(size_t)gm * N + gn] = f2bf(gl);
                } else {
                    outf[(size_t)gm * N + gn] = res[(size_t)gm * N + gn] + ls[gn] * val;
                }
            }
        }
    }
}

// ---------------- V transpose: qkv_buf v-part -> Vt [B,H,D,T] ----------------
__global__ __launch_bounds__(256) void vtrans_kernel(const u16* __restrict__ qkv,
                                                     u16* __restrict__ vt) {
    __shared__ u16 tile[64 * 72];
    int t0 = blockIdx.x * 64, h = blockIdx.y, b = blockIdx.z;
    int tid = threadIdx.x;
#pragma unroll
    for (int i = 0; i < 2; i++) {
        int c = tid + i * 256, tr = c >> 3, j = c & 7;
        bf16x8 v = *(const bf16x8*)(qkv + (size_t)(b * T_ + t0 + tr) * N3C + 1536 + h * 64 + j * 8);
        *(bf16x8*)(tile + tr * 72 + j * 8) = v;
    }
    __syncthreads();
#pragma unroll
    for (int i = 0; i < 2; i++) {
        int c = tid + i * 256, d = c >> 3, tj = c & 7;
        bf16x8 o;
#pragma unroll
        for (int k = 0; k < 8; k++) o[k] = (short)tile[(tj * 8 + k) * 72 + d];
        *(bf16x8*)(vt + (size_t)((b * H_ + h) * 64 + d) * T_ + t0 + tj * 8) = o;
    }
}

// ---------------- fused attention, v8 = R6 structure + nontemporal streams ----------------
// R9 killed the in-flight hypothesis (8 designs, all ~2 TB/s). Last distinct
// lever: L2 policy. bias (402MB read-once) and attn_out (402MB write-once)
// are pure streams cycling the 32MB L2 via allocate+evict; nt loads/stores
// bypass L2 allocation. Only two edits vs the 356us R6 kernel.
__global__ __launch_bounds__(256, 2) void attn_kernel(const u16* __restrict__ qkv,
                                                      const u16* __restrict__ vt,
                                                      const float* __restrict__ bias,
                                                      const float* __restrict__ mask,
                                                      float* __restrict__ attn_out,
                                                      u16* __restrict__ ybuf) {
    __shared__ u16 S[16 * 2048];     // bf16 scaled logits, then bf16 P in place
    __shared__ float rinv_lds[16];
    char* Sb = (char*)S;
    int qt = blockIdx.x, h = blockIdx.y, b = blockIdx.z;
    int tid = threadIdx.x, lane = tid & 63, wid = tid >> 6;
    int lr = lane & 15, lq = lane >> 4;
    int q0 = qt * 16;
    size_t bh = (size_t)(b * H_ + h);
    const float scale = 0.125f;

    // ---- A1: S = bf16(QK^T * scale) via swapped mfma(K,Q); wave w owns cols w*512.. ----
    const u16* qp = qkv + (size_t)(b * T_ + q0 + lr) * N3C + h * 64;
    bf16x8 qa0 = *(const bf16x8*)(qp + lq * 8);
    bf16x8 qa1 = *(const bf16x8*)(qp + 32 + lq * 8);
    const u16* kbase = qkv + (size_t)(b * T_ + wid * 512 + lr) * N3C + 768 + h * 64 + lq * 8;
#pragma unroll 4
    for (int ct = 0; ct < 32; ++ct) {
        bf16x8 kf0 = *(const bf16x8*)(kbase + (size_t)ct * 16 * N3C);
        bf16x8 kf1 = *(const bf16x8*)(kbase + (size_t)ct * 16 * N3C + 32);
        f32x4 a = (f32x4){0.f, 0.f, 0.f, 0.f};
        a = __builtin_amdgcn_mfma_f32_16x16x32_bf16(kf0, qa0, a, 0, 0, 0);
        a = __builtin_amdgcn_mfma_f32_16x16x32_bf16(kf1, qa1, a, 0, 0, 0);
        int colbase = wid * 512 + ct * 16;   // lane holds S[lr][colbase+lq*4 ..+3]
        ushort4 pk;
        pk.x = f2bf(a[0] * scale);
        pk.y = f2bf(a[1] * scale);
        pk.z = f2bf(a[2] * scale);
        pk.w = f2bf(a[3] * scale);
        *(ushort4*)(Sb + (((u32)lr * 4096 + 2 * colbase + 8 * lq) ^ ((lr & 7) << 4))) = pk;
    }
    __syncthreads();

    // ---- A2: P = exp(S + bias + mask), rows batched; bias via NT loads ----
    const float* bb = bias + (bh * T_ + q0 + wid * 4) * T_;
    const float* mb = mask + ((size_t)b * T_ + q0 + wid * 4) * T_;
    float lsum4[4] = {0.f, 0.f, 0.f, 0.f};
#pragma unroll
    for (int ch = 0; ch < 8; ++ch) {
        int col = ch * 256 + lane * 4;           // 64 lanes = 1KB contiguous per row
        f32x4 b4[4];
        float4 m4[4];
#pragma unroll
        for (int rr = 0; rr < 4; ++rr) {         // 8 independent dwordx4 loads issue here
            b4[rr] = __builtin_nontemporal_load((const f32x4*)(bb + (size_t)rr * T_ + col));
            m4[rr] = *(const float4*)(mb + (size_t)rr * T_ + col);
        }
#pragma unroll
        for (int rr = 0; rr < 4; ++rr) {
            int r = wid * 4 + rr;
            u32 addr = ((u32)r * 4096 + (u32)col * 2) ^ ((u32)(r & 7) << 4);
            uint2 s2 = *(const uint2*)(Sb + addr);
            float e0 = __expf(__uint_as_float(s2.x << 16) + b4[rr][0] + m4[rr].x);
            float e1 = __expf(__uint_as_float(s2.x & 0xffff0000u) + b4[rr][1] + m4[rr].y);
            float e2 = __expf(__uint_as_float(s2.y << 16) + b4[rr][2] + m4[rr].z);
            float e3 = __expf(__uint_as_float(s2.y & 0xffff0000u) + b4[rr][3] + m4[rr].w);
            lsum4[rr] += (e0 + e1) + (e2 + e3);
            uint2 o;
            o.x = ((u32)f2bf(e1) << 16) | (u32)f2bf(e0);
            o.y = ((u32)f2bf(e3) << 16) | (u32)f2bf(e2);
            *(uint2*)(Sb + addr) = o;                // in-place bf16 P
        }
    }
    float rinv_r[4];
#pragma unroll
    for (int rr = 0; rr < 4; ++rr) {
        float ls = lsum4[rr];
        for (int m = 32; m; m >>= 1) ls += __shfl_xor(ls, m);
        rinv_r[rr] = 1.f / ls;
        if (lane == 0) rinv_lds[wid * 4 + rr] = rinv_r[rr];
    }
    __syncthreads();

    // ---- A3: attn_out = P * rinv via NT stores (write-once stream) ----
    float* ao_base = attn_out + (bh * T_ + q0 + wid * 4) * T_;
#pragma unroll
    for (int ch = 0; ch < 8; ++ch) {
        int col = ch * 256 + lane * 4;
#pragma unroll
        for (int rr = 0; rr < 4; ++rr) {
            int r = wid * 4 + rr;
            u32 addr = ((u32)r * 4096 + (u32)col * 2) ^ ((u32)(r & 7) << 4);
            uint2 s2 = *(const uint2*)(Sb + addr);
            float rv = rinv_r[rr];
            f32x4 o;
            o[0] = __uint_as_float(s2.x << 16) * rv;
            o[1] = __uint_as_float(s2.x & 0xffff0000u) * rv;
            o[2] = __uint_as_float(s2.y << 16) * rv;
            o[3] = __uint_as_float(s2.y & 0xffff0000u) * rv;
            __builtin_nontemporal_store(o, (f32x4*)(ao_base + (size_t)rr * T_ + col));
        }
    }

    // ---- C: y = (P @ V) * rinv; wave w owns d-cols 16w..16w+15 ----
    f32x4 acc = (f32x4){0.f, 0.f, 0.f, 0.f};
    const u16* vtp = vt + (bh * 64 + wid * 16 + lr) * (size_t)T_ + lq * 8;
#pragma unroll 4
    for (int ks = 0; ks < 64; ++ks) {
        bf16x8 pf = *(const bf16x8*)(Sb + (((u32)lr * 4096 + ks * 64 + lq * 16) ^ ((lr & 7) << 4)));
        bf16x8 vf = *(const bf16x8*)(vtp + ks * 32);
        acc = __builtin_amdgcn_mfma_f32_16x16x32_bf16(pf, vf, acc, 0, 0, 0);
    }
#pragma unroll
    for (int r = 0; r < 4; r++) {
        int row = lq * 4 + r;
        float y = acc[r] * rinv_lds[row];
        ybuf[(size_t)(b * T_ + q0 + row) * C_ + h * 64 + wid * 16 + lr] = f2bf(y);
    }
}

// ---------------- host ----------------
extern "C" void kernel_launch(void* const* d_in, const int* in_sizes, int n_in,
                              void* d_out, int out_size, void* d_ws, size_t ws_size,
                              hipStream_t stream) {
    const float* x = (const float*)d_in[0];
    const float* mask = (const float*)d_in[1];
    const float* bias = (const float*)d_in[2];
    const float* ln1g = (const float*)d_in[3];
    const float* ln1b = (const float*)d_in[4];
    const float* qkvw = (const float*)d_in[5];
    const float* qkvb = (const float*)d_in[6];
    const float* projw = (const float*)d_in[7];
    const float* projb = (const float*)d_in[8];
    const float* ls1 = (const float*)d_in[9];
    const float* ln2g = (const float*)d_in[10];
    const float* ln2b = (const float*)d_in[11];
    const float* w1 = (const float*)d_in[12];
    const float* b1 = (const float*)d_in[13];
    const float* w2 = (const float*)d_in[14];
    const float* b2 = (const float*)d_in[15];
    const float* ls2 = (const float*)d_in[16];

    char* ws = (char*)d_ws;
    size_t off = 0;
    u16* qkvw_b = (u16*)(ws + off); off += (size_t)N3C * C_ * 2;
    u16* projw_b = (u16*)(ws + off); off += (size_t)C_ * C_ * 2;
    u16* w1_b = (u16*)(ws + off); off += (size_t)HID_ * C_ * 2;
    u16* w2_b = (u16*)(ws + off); off += (size_t)C_ * HID_ * 2;
    u16* xn = (u16*)(ws + off); off += (size_t)NROW * C_ * 2;          // reused as hn after attn
    u16* qkvbuf = (u16*)(ws + off); off += (size_t)NROW * N3C * 2;     // } contiguous; reused as
    u16* vt = (u16*)(ws + off); off += (size_t)B_ * H_ * D_ * T_ * 2;  // } g [4096,3072] after attn
    u16* g = qkvbuf;
    u16* ybuf = (u16*)(ws + off); off += (size_t)NROW * C_ * 2;
    float* x1 = (float*)(ws + off); off += (size_t)NROW * C_ * 4;
    (void)ws_size; (void)n_in; (void)in_sizes; (void)out_size;

    float* outx = (float*)d_out;
    float* attn_out = outx + (size_t)NROW * C_;

    // weights -> bf16
    cvt_bf16_kernel<<<(N3C * C_ / 4 + 255) / 256, 256, 0, stream>>>(qkvw, qkvw_b, N3C * C_);
    cvt_bf16_kernel<<<(C_ * C_ / 4 + 255) / 256, 256, 0, stream>>>(projw, projw_b, C_ * C_);
    cvt_bf16_kernel<<<(HID_ * C_ / 4 + 255) / 256, 256, 0, stream>>>(w1, w1_b, HID_ * C_);
    cvt_bf16_kernel<<<(C_ * HID_ / 4 + 255) / 256, 256, 0, stream>>>(w2, w2_b, C_ * HID_);

    // LN1
    ln_kernel<<<NROW, 256, 0, stream>>>(x, ln1g, ln1b, xn);
    // QKV
    gemm_kernel<0><<<dim3(N3C / 128, NROW / 128), 256, 0, stream>>>(
        xn, qkvw_b, qkvb, nullptr, qkvbuf, nullptr, nullptr, N3C, C_);
    // V transpose
    vtrans_kernel<<<dim3(T_ / 64, H_, B_), 256, 0, stream>>>(qkvbuf, vt);
    // fused attention
    attn_kernel<<<dim3(T_ / 16, H_, B_), 256, 0, stream>>>(qkvbuf, vt, bias, mask, attn_out, ybuf);
    // proj + residual*ls1 -> x1
    gemm_kernel<2><<<dim3(C_ / 128, NROW / 128), 256, 0, stream>>>(
        ybuf, projw_b, projb, x1, nullptr, x, ls1, C_, C_);
    // LN2
    ln_kernel<<<NROW, 256, 0, stream>>>(x1, ln2g, ln2b, xn);
    // MLP1 + gelu
    gemm_kernel<1><<<dim3(HID_ / 128, NROW / 128), 256, 0, stream>>>(
        xn, w1_b, b1, nullptr, g, nullptr, nullptr, HID_, C_);
    // MLP2 + residual*ls2 -> out
    gemm_kernel<2><<<dim3(C_ / 128, NROW / 128), 256, 0, stream>>>(
        g, w2_b, b2, outx, nullptr, x1, ls2, C_, HID_);
}